// Round 12
// baseline (421.497 us; speedup 1.0000x reference)
//
#include <hip/hip_runtime.h>
#include <math.h>

// SimpleRetention bf16 MFMA, round 15:
//  - s4: BN=64, 2048 blocks (8/CU, was 4/CU) — the stage is latency-bound
//    (avg 5.6 k-iters/block), so fill doubles latency hiding. XCD-chunk 8x256.
//  - cvt: W-transpose retiled to 128x64 with us4 stores (256B runs).
//  - Everything else frozen from round 14 (411.0 us): s1a Q,K only; fused
//    att+V overlap; banded att (384 cols, 2by-4); proven 128-row BK=64 core.

typedef __attribute__((ext_vector_type(8))) short short8;
typedef __attribute__((ext_vector_type(4))) float f32x4;
typedef __attribute__((ext_vector_type(4))) unsigned short us4;

#define BM 128
#define ABAND 384

static __device__ __forceinline__ unsigned short f2bf(float f) {
    unsigned int u = __float_as_uint(f);
    u += 0x7FFFu + ((u >> 16) & 1u);   // RNE
    return (unsigned short)(u >> 16);
}

static __device__ __forceinline__ void gload16(const unsigned short* g, unsigned short* l) {
    __builtin_amdgcn_global_load_lds(
        (const __attribute__((address_space(1))) unsigned int*)g,
        (__attribute__((address_space(3))) unsigned int*)l, 16, 0, 0);
}

// STAGE: 1 = QKV projection epilogues (mode by colBase: Q/K xpos, V transpose)
//        3 = att_b = (Q K^T)*decay (banded storage)
//        4 = out = att_b x V (banded k-loop)
template <int STAGE, int BNt, int BKt>
static __device__ __forceinline__ void gemm_core(
    const unsigned short* __restrict__ A,
    const unsigned short* __restrict__ Bt,
    void* __restrict__ Cv,
    unsigned short* __restrict__ Cq,
    unsigned short* __restrict__ Ck,
    unsigned short* __restrict__ Cvt,
    int lda, int ldb, int Kd,
    long long sA, long long sB, long long sC,
    int bx, int by, int zb,
    unsigned short* As, unsigned short* Bs)
{
    constexpr int S = 2048, H = 2048;
    constexpr int NJ = BNt / 32;        // j-fragments per wave
    constexpr int KS = BKt / 32;        // MFMA k-steps per tile
    constexpr int CR = BKt / 8;         // 16B chunks per row
    constexpr int RG = 64 / CR;         // rows per gload16
    constexpr int GA = 32 / RG;         // A gloads per thread
    constexpr int GB = (BNt / 4) / RG;  // B gloads per thread

    const int rowBase = by * BM;
    const int colBase = bx * BNt;

    A  += (long long)zb * sA;
    Bt += (long long)zb * sB;

    const int tid  = threadIdx.x;
    const int wave = tid >> 6;
    const int lane = tid & 63;
    const int wm = (wave & 1) * 64;
    const int wn = (wave >> 1) * (BNt / 2);

    f32x4 acc[4][NJ];
#pragma unroll
    for (int i = 0; i < 4; ++i)
#pragma unroll
        for (int j = 0; j < NJ; ++j) acc[i][j] = (f32x4){0.f, 0.f, 0.f, 0.f};

    int kmax = Kd;
    if (STAGE == 4) { int km = rowBase + BM; kmax = km < Kd ? km : Kd; } // causal
    int k0s = 0;
    if (STAGE == 4) {
        int kb0 = 2 * by - 4; k0s = (kb0 > 0 ? kb0 : 0) * 64;
        A -= k0s;   // banded storage: att_b[n][k - k0s] == dense att[n][k]
    }

    // Staging invariant: LDS chunk position p of row r holds source chunk
    // p ^ (r&7).  cpos = dest chunk, rig = row within gload group.
    const int cpos = lane % CR;
    const int rig  = lane / CR;
    const int waveArow = wave * 32;
    const int waveBrow = wave * (BNt / 4);
    unsigned short* lA = As + wave * (32 * BKt);
    unsigned short* lB = Bs + wave * ((BNt / 4) * BKt);

    auto stage_tile = [&](int kb) {
#pragma unroll
        for (int g = 0; g < GA; ++g) {
            int r = waveArow + g * RG + rig;
            gload16(A + (size_t)(rowBase + r) * lda + kb + ((cpos ^ (r & 7)) * 8),
                    lA + g * 512);
        }
#pragma unroll
        for (int g = 0; g < GB; ++g) {
            int r = waveBrow + g * RG + rig;
            gload16(Bt + (size_t)(colBase + r) * ldb + kb + ((cpos ^ (r & 7)) * 8),
                    lB + g * 512);
        }
    };

    stage_tile(k0s);

    const int fr = lane & 15;
    const int qd = lane >> 4;        // k-quad within 32-k step
    const int fsw = fr & 7;          // xor key per fragment row

    for (int k0 = k0s; k0 < kmax; k0 += BKt) {
        __syncthreads(); // tile k0 resident
        short8 aF[KS][4], bF[KS][NJ];
#pragma unroll
        for (int kk = 0; kk < KS; ++kk) {
#pragma unroll
            for (int i = 0; i < 4; ++i)
                aF[kk][i] = *(const short8*)&As[(wm + i * 16 + fr) * BKt + (((kk * 4 + qd) ^ fsw) * 8)];
#pragma unroll
            for (int j = 0; j < NJ; ++j)
                bF[kk][j] = *(const short8*)&Bs[(wn + j * 16 + fr) * BKt + (((kk * 4 + qd) ^ fsw) * 8)];
        }
        __syncthreads(); // all reads drained
        if (k0 + BKt < kmax) stage_tile(k0 + BKt);
#pragma unroll
        for (int kk = 0; kk < KS; ++kk)
#pragma unroll
            for (int i = 0; i < 4; ++i)
#pragma unroll
                for (int j = 0; j < NJ; ++j)
                    acc[i][j] = __builtin_amdgcn_mfma_f32_16x16x32_bf16(aF[kk][i], bF[kk][j], acc[i][j], 0, 0, 0);
    }

    // C/D layout: col = lane&15, row = (lane>>4)*4 + reg
    if (STAGE == 1) {
        const int mode = colBase >> 11; // 0=Q, 1=K, 2=V
        if (mode < 2) {
            unsigned short* Co = (mode == 0) ? Cq : Ck;
            const float psgn = (mode == 1) ? -1.953125e-3f : 1.953125e-3f; // ±1/512
#pragma unroll
            for (int j = 0; j < NJ; ++j) {
                int gc = (colBase & 2047) + wn + j * 16 + fr;
                float c0 = (float)(gc & ~1);
                float l2sv = log2f((c0 + 819.2f) * (1.0f / 2867.2f)) * psgn;
                float invf = exp2f(c0 * -0.0064881407f); // 10000^(-c0/2048)
                float s1, c1;
                sincosf(invf, &s1, &c1);
#pragma unroll
                for (int i = 0; i < 4; ++i) {
                    int gr0 = rowBase + wm + i * 16 + qd * 4;
                    float fn = (float)(gr0 & (S - 1));
                    float sN, cN;
                    sincosf(fn * invf, &sN, &cN);
#pragma unroll
                    for (int r = 0; r < 4; ++r) {
                        float scale = exp2f(fn * l2sv);
                        float cs = cN * scale, ss = sN * scale;
                        float v = acc[i][j][r];
                        float o = __shfl_xor(v, 1);
                        float res = (gc & 1) ? fmaf(v, cs, o * ss) : fmaf(v, cs, -o * ss);
                        Co[(size_t)(gr0 + r) * H + gc] = f2bf(res);
                        float sn2 = sN * c1 + cN * s1; // rotate by invf
                        cN = cN * c1 - sN * s1;
                        sN = sn2;
                        fn += 1.0f;
                    }
                }
            }
        } else { // V: store transposed Vt[h][8192]
#pragma unroll
            for (int j = 0; j < NJ; ++j) {
                int gh = (colBase & 2047) + wn + j * 16 + fr;
#pragma unroll
                for (int i = 0; i < 4; ++i) {
                    int gm0 = rowBase + wm + i * 16 + qd * 4;
                    us4 p;
#pragma unroll
                    for (int r = 0; r < 4; ++r) p[r] = f2bf(acc[i][j][r]);
                    *(us4*)&Cvt[(size_t)gh * 8192 + gm0] = p;
                }
            }
        }
    } else if (STAGE == 3) {
        unsigned short* att = (unsigned short*)Cv + (long long)zb * sC;
        const int kb0 = (2 * by - 4) > 0 ? (2 * by - 4) : 0;  // storage shift
        const int mshift = kb0 * 64;
#pragma unroll
        for (int j = 0; j < NJ; ++j) {
            int m = colBase + wn + j * 16 + fr;
#pragma unroll
            for (int i = 0; i < 4; ++i) {
                int n0 = rowBase + wm + i * 16 + qd * 4;
#pragma unroll
                for (int r = 0; r < 4; ++r) {
                    int d = n0 + r - m;
                    float v = (d >= 0) ? acc[i][j][r] * exp2f((float)d * -0.045803598f) : 0.0f;
                    att[(size_t)(n0 + r) * ABAND + (m - mshift)] = f2bf(v);
                }
            }
        }
    } else { // STAGE 4: C rows = n, cols = h -> out[n][h], 64B lane-runs
        float* Co = (float*)Cv + (long long)zb * sC;
#pragma unroll
        for (int j = 0; j < NJ; ++j) {
            int gh = colBase + wn + j * 16 + fr;
#pragma unroll
            for (int i = 0; i < 4; ++i) {
                int gn0 = rowBase + wm + i * 16 + qd * 4;
#pragma unroll
                for (int r = 0; r < 4; ++r)
                    Co[(size_t)(gn0 + r) * H + gh] = acc[i][j][r];
            }
        }
    }
}

// s1a (STAGE=1, Q/K cols only) and s4 (STAGE=4, XCD-chunked) wrappers
template <int STAGE, int BNt, int BKt>
__global__ __launch_bounds__(256)
void gemm_bt(const unsigned short* __restrict__ A,
             const unsigned short* __restrict__ Bt,
             void* __restrict__ Cv,
             unsigned short* __restrict__ Cq,
             unsigned short* __restrict__ Ck,
             unsigned short* __restrict__ Cvt,
             int lda, int ldb, int Kd,
             long long sA, long long sB, long long sC)
{
    __shared__ unsigned short As[BM * BKt];
    __shared__ unsigned short Bs[BNt * BKt];
    int bx, by, zb;
    if (STAGE == 4) {
        // XCD-chunked (2048 = 8*256): each chunk = 4 Vt h-slabs;
        // within chunk: bx-major, then batch, then by descending (LPT).
        int id = blockIdx.x;
        int swz = (id & 7) * 256 + (id >> 3);
        bx = swz >> 6;
        int r = swz & 63;
        zb = r >> 4;
        by = 15 - (r & 15);
    } else {
        bx = blockIdx.x; by = blockIdx.y; zb = 0;
    }
    gemm_core<STAGE, BNt, BKt>(A, Bt, Cv, Cq, Ck, Cvt, lda, ldb, Kd,
                               sA, sB, sC, bx, by, zb, As, Bs);
}

// Fused: ids [0,360) = att blocks (latency-bound, spread first);
//        ids [360,1384) = V-projection blocks (backfill, hide att latency).
__global__ __launch_bounds__(256)
void fused_vatt(const unsigned short* __restrict__ Xb,
                const unsigned short* __restrict__ Wt,
                const unsigned short* __restrict__ Qb,
                const unsigned short* __restrict__ Kb,
                unsigned short* __restrict__ att,
                unsigned short* __restrict__ Vt)
{
    constexpr int S = 2048, H = 2048;
    constexpr long long SH = (long long)S * H;
    constexpr long long SB = (long long)S * ABAND;
    __shared__ unsigned short smem[16384];   // As 8192 + Bs up to 8192
    if (blockIdx.x < 360) {
        // att: XCD-chunked (360 = 8*45) + banded lower-tri decode (2by-4)
        int t = blockIdx.x;
        int swz = (t & 7) * 45 + (t >> 3);
        int zb = swz / 90;
        int tt = swz - zb * 90;
        int bx, by;
        if (tt < 6) {
            by = (tt < 2) ? 0 : 1;
            bx = tt - ((by == 0) ? 0 : 2);
        } else {
            by = 2 + (tt - 6) / 6;
            int kb0 = 2 * by - 4;
            bx = (kb0 > 0 ? kb0 : 0) + (tt - 6) % 6;
        }
        gemm_core<3, 64, 64>(Qb, Kb, att, nullptr, nullptr, nullptr,
                             H, H, H, SH, SH, SB, bx, by, zb,
                             smem, smem + 8192);
    } else {
        int id = blockIdx.x - 360;           // 0..1023
        int bx = 32 + (id & 15);             // V columns: colBase >= 4096
        int by = id >> 4;
        gemm_core<1, 128, 64>(Xb, Wt, nullptr, nullptr, nullptr, Vt,
                              H, H, H, 0, 0, 0, bx, by, 0,
                              smem, smem + 8192);
    }
}

// Fused conversions: blocks [0,1536) transpose W0..W2 -> WtAll bf16
// (128-row x 64-col tiles, us4 stores = 256B runs);
// blocks [1536, 3584) convert X fp32 -> bf16 (32 elems/thread).
__global__ __launch_bounds__(256)
void cvt_fused(const float* __restrict__ X, unsigned short* __restrict__ Xb,
               const float* __restrict__ W0, const float* __restrict__ W1,
               const float* __restrict__ W2, unsigned short* __restrict__ Wt) {
    __shared__ float t[64][129];  // [src col][src row]
    if (blockIdx.x < 1536) {
        int id = blockIdx.x;
        int z = id >> 9, rem = id & 511;     // 512 = 16 row-grp x 32 col-grp
        const float* W = (z == 0) ? W0 : (z == 1) ? W1 : W2;
        unsigned short* Wo = Wt + (size_t)z * 4194304;
        int rowB = (rem >> 5) * 128;         // source row group (16)
        int colB = (rem & 31) * 64;          // source col group (32)
        int tx = threadIdx.x & 63, ty = threadIdx.x >> 6;
#pragma unroll
        for (int r = 0; r < 128; r += 4)
            t[tx][ty + r] = W[(size_t)(rowB + ty + r) * 2048 + colB + tx];
        __syncthreads();
        int rq = (threadIdx.x & 31) * 4;     // output-row quad (covers 128)
        int cq = threadIdx.x >> 5;           // 0..7
#pragma unroll
        for (int c8 = 0; c8 < 8; ++c8) {
            int c = cq * 8 + c8;
            us4 p = { f2bf(t[c][rq]), f2bf(t[c][rq + 1]),
                      f2bf(t[c][rq + 2]), f2bf(t[c][rq + 3]) };
            *(us4*)&Wo[(size_t)(colB + c) * 2048 + rowB + rq] = p;
        }
    } else {
        int id = blockIdx.x - 1536;          // 0..2047
        const float4* X4 = (const float4*)X;
        short8* O8 = (short8*)Xb;
#pragma unroll
        for (int c = 0; c < 4; ++c) {
            size_t u = (size_t)c * (2048 * 256) + (size_t)id * 256 + threadIdx.x;
            float4 a = X4[u * 2];
            float4 b = X4[u * 2 + 1];
            short8 o;
            o[0] = f2bf(a.x); o[1] = f2bf(a.y); o[2] = f2bf(a.z); o[3] = f2bf(a.w);
            o[4] = f2bf(b.x); o[5] = f2bf(b.y); o[6] = f2bf(b.z); o[7] = f2bf(b.w);
            O8[u] = o;
        }
    }
}

extern "C" void kernel_launch(void* const* d_in, const int* in_sizes, int n_in,
                              void* d_out, int out_size, void* d_ws, size_t ws_size,
                              hipStream_t stream) {
    const int S = 2048, H = 2048;
    const long long MH = 16777216;         // 8192*2048 elements
    const long long HH = 4194304;          // 2048*2048
    const long long SB = (long long)S * ABAND; // banded att per-batch stride
    const long long SH = (long long)S * H;     // per-batch stride

    const float* X  = (const float*)d_in[0];
    const float* WQ = (const float*)d_in[1];
    const float* WK = (const float*)d_in[2];
    const float* WV = (const float*)d_in[3];
    float* out = (float*)d_out;

    unsigned short* Xb    = (unsigned short*)d_ws;
    unsigned short* WtAll = Xb + MH;        // [6144][2048]
    unsigned short* Qb    = WtAll + 3 * HH;
    unsigned short* Kb    = Qb + MH;
    unsigned short* Vt    = Kb + MH;        // [2048][8192]
    unsigned short* att   = Vt + MH;        // [4][2048][384] banded

    cvt_fused<<<3584, 256, 0, stream>>>(X, Xb, WQ, WK, WV, WtAll);

    // s1a: Q,K projection only (N = 4096)
    gemm_bt<1, 128, 64><<<dim3(32, 64), 256, 0, stream>>>(Xb, WtAll, nullptr, Qb, Kb, Vt,
                                                          H, H, H, 0, 0, 0);
    // fused: att (360 blocks, first) + V-projection (1024 blocks, backfill)
    fused_vatt<<<1384, 256, 0, stream>>>(Xb, WtAll, Qb, Kb, att, Vt);

    // s4: out = att_b x V, banded k-loop, BN=64, XCD-chunked (2048 = 8*256)
    gemm_bt<4, 64, 64><<<2048, 256, 0, stream>>>(att, Vt, out, nullptr, nullptr, nullptr,
                                                 ABAND, 8192, S, SB, 2048, SH);
}